// Round 4
// baseline (795.711 us; speedup 1.0000x reference)
//
#include <hip/hip_runtime.h>
#include <hip/hip_fp16.h>
#include <math.h>

#define NX   160
#define N2   25600        // 160*160
#define N3   4096000      // 160^3
#define NB   4

#define NTILES_XY 16000   // 5*5*160*4 blocks
#define TILES_PER_B 4000  // 5*5*160
#define NBLK_Z 800        // 40 x4 * 160 y * 8 zc * 4 b / 256

#define SB_W 36           // 32 cols + 4 pad floats (144 B, 16B-aligned rows)

// 1D Gaussian taps exp(-d^2/50), d=-4..4 (NOT normalized, matches reference)
__device__ __constant__ float G1[9] = {
    0.72614903f, 0.83527021f, 0.92311635f, 0.98019867f, 1.0f,
    0.98019867f, 0.92311635f, 0.83527021f, 0.72614903f};

// edge sums: FULL - missing taps at low/high boundary
#define ES_FULL 7.92946852f
__device__ __constant__ float ES_M[4] = {3.46473426f, 2.48453559f, 1.56141924f,
                                         0.72614903f};
__device__ inline float edge_sum(int i) {
    float s = ES_FULL;
    if (i < 4) s -= ES_M[i];
    if (i > NX - 5) s -= ES_M[NX - 1 - i];
    return s;
}

__device__ inline float4 f4_zero() { return make_float4(0.f, 0.f, 0.f, 0.f); }
__device__ inline float4 f4_axpy(float a, float4 b, float4 c) {
    return make_float4(c.x + a * b.x, c.y + a * b.y, c.z + a * b.z, c.w + a * b.w);
}

__device__ inline float4 load_t4(const __half* p) {
    uint2 u = *(const uint2*)p;
    __half2 a = *(const __half2*)&u.x;
    __half2 b = *(const __half2*)&u.y;
    float2 fa = __half22float2(a);
    float2 fb = __half22float2(b);
    return make_float4(fa.x, fa.y, fb.x, fb.y);
}

// block = 256 threads. Reduce NV doubles into thread 0's vals[]. Safe to call
// repeatedly (trailing barrier protects the shared scratch).
template <int NV>
__device__ inline void block_reduce_to_t0(double* vals) {
    __shared__ double red[4][NV];
    int lane = threadIdx.x & 63;
    int wave = threadIdx.x >> 6;
#pragma unroll
    for (int v = 0; v < NV; ++v) {
        double x = vals[v];
#pragma unroll
        for (int off = 32; off > 0; off >>= 1) x += __shfl_down(x, off, 64);
        if (lane == 0) red[wave][v] = x;
    }
    __syncthreads();
    if (threadIdx.x == 0) {
#pragma unroll
        for (int v = 0; v < NV; ++v)
            vals[v] = red[0][v] + red[1][v] + red[2][v] + red[3][v];
    }
    __syncthreads();
}

// x-conv straight from global (L1 absorbs the 3x float4 overlap), y-conv via
// small sB LDS, t stored as fp16. Fused per-batch sums; last block reduces
// pS -> S (means numer/denoms) via atomic ticket.
__global__ __launch_bounds__(256) void conv_xy_kernel(
    const float* __restrict__ labels, const float* __restrict__ inputs,
    __half* __restrict__ t, double* __restrict__ pS, double* __restrict__ S,
    int* __restrict__ cnt) {
    __shared__ float sB[40 * SB_W];

    int bid = blockIdx.x;
    int tileX = bid % 5;
    int tileY = (bid / 5) % 5;
    int zb = bid / 25;            // z + 160*b
    int sliceOff = zb * N2;       // == b*N3 + z*N2
    int x0 = tileX * 32, y0 = tileY * 32;
    int tid = threadIdx.x;

    // phase 1: x-conv, 40 rows x 8 float4 outputs, inputs from global
    for (int i = tid; i < 320; i += 256) {
        int r = i >> 3, x4 = i & 7;
        int gy = y0 + r - 4;
        int gxf = x0 + 4 * x4 - 4;   // window start (multiple of 4)
        float w[12];
        if (gy >= 0 && gy < NX) {
            const float* row = &labels[sliceOff + gy * NX];
#pragma unroll
            for (int c = 0; c < 3; ++c) {
                int gx = gxf + 4 * c;
                float4 v = (gx >= 0 && gx <= NX - 4) ? *(const float4*)&row[gx]
                                                     : f4_zero();
                w[4 * c] = v.x; w[4 * c + 1] = v.y;
                w[4 * c + 2] = v.z; w[4 * c + 3] = v.w;
            }
        } else {
#pragma unroll
            for (int c = 0; c < 12; ++c) w[c] = 0.f;
        }
        float4 o = f4_zero();
#pragma unroll
        for (int d = 0; d < 9; ++d) {
            float g = G1[d];
            o.x += g * w[d];
            o.y += g * w[d + 1];
            o.z += g * w[d + 2];
            o.w += g * w[d + 3];
        }
        *(float4*)&sB[r * SB_W + 4 * x4] = o;
    }
    __syncthreads();

    // phase 2: y-conv (one float4 per thread) + fp16 store + fused sums
    int oy = tid >> 3, x4 = tid & 7;
    float4 acc = f4_zero();
#pragma unroll
    for (int d = 0; d < 9; ++d) {
        float4 v = *(const float4*)&sB[(oy + d) * SB_W + 4 * x4];
        acc = f4_axpy(G1[d], v, acc);
    }
    int gi = sliceOff + (y0 + oy) * NX + (x0 + 4 * x4);
    __half2 ha = __floats2half2_rn(acc.x, acc.y);
    __half2 hb = __floats2half2_rn(acc.z, acc.w);
    uint2 u;
    u.x = *(unsigned int*)&ha;
    u.y = *(unsigned int*)&hb;
    *(uint2*)&t[gi] = u;   // byte offset 2*gi, gi%4==0 -> 8B aligned

    float4 p = *(const float4*)&labels[gi];
    float4 in = *(const float4*)&inputs[gi];
    double vals[3];
    vals[0] = (double)(p.x + p.y + p.z + p.w);
    vals[1] = (double)(in.x * p.x + in.y * p.y + in.z * p.z + in.w * p.w);
    vals[2] = (double)(in.x + in.y + in.z + in.w);
    block_reduce_to_t0<3>(vals);

    __shared__ int lastFlag;
    if (tid == 0) {
        pS[bid * 3 + 0] = vals[0];
        pS[bid * 3 + 1] = vals[1];
        pS[bid * 3 + 2] = vals[2];
        __threadfence();
        int ticket = atomicAdd(cnt, 1);
        lastFlag = (ticket == NTILES_XY - 1);
    }
    __syncthreads();
    if (lastFlag) {
        __threadfence();
        for (int b = 0; b < NB; ++b) {
            double a0 = 0, a1 = 0, a2 = 0;
            for (int i = tid; i < TILES_PER_B; i += 256) {
                const double* p2 = &pS[(b * TILES_PER_B + i) * 3];
                a0 += p2[0]; a1 += p2[1]; a2 += p2[2];
            }
            double v[3] = {a0, a1, a2};
            block_reduce_to_t0<3>(v);
            if (tid == 0) {
                S[3 * b + 0] = v[0];
                S[3 * b + 1] = v[1];
                S[3 * b + 2] = v[2];
            }
        }
    }
}

// z-conv via register sliding window (float4 = 4 x-cols), t in fp16, batched
// loads (4 z-steps, 12 loads in flight). Last block reduces pZ and writes loss.
__global__ __launch_bounds__(256) void conv_z_kernel(
    const __half* __restrict__ t, const float* __restrict__ labels,
    const float* __restrict__ inputs, const double* __restrict__ S,
    double* __restrict__ pZ, float* __restrict__ out, int* __restrict__ cnt) {
    int tid = threadIdx.x;
    int tidg = blockIdx.x * 256 + tid;  // 0 .. 204799
    int x4 = tidg % 40;           // float4 column; x = 4*x4
    int r = tidg / 40;
    int y = r % NX;
    r /= NX;
    int zc = r % 8;               // z chunk of 20
    int b = r / 8;

    // per-batch means (class 0: p, class 1: 1-p)
    double sp = S[3 * b + 0], sip = S[3 * b + 1], si = S[3 * b + 2];
    const double Nv = (double)N3;
    float m0 = (float)((sip / Nv) / (sp / Nv + 1e-5));
    float m1 = (float)(((si - sip) / Nv) / ((Nv - sp) / Nv + 1e-5));

    int x = x4 * 4;
    float ey = edge_sum(y);
    float cx[4] = {edge_sum(x) * ey, edge_sum(x + 1) * ey,
                   edge_sum(x + 2) * ey, edge_sum(x + 3) * ey};

    int z0 = zc * 20;
    int base = b * N3 + y * NX + x;

    float4 win[9];
#pragma unroll
    for (int d = 0; d < 9; ++d) {
        int z = z0 - 4 + d;
        win[d] = (z >= 0 && z < NX) ? load_t4(&t[base + z * N2]) : f4_zero();
    }

    float n0 = 0.f, d0 = 0.f, n1 = 0.f, d1 = 0.f;
    for (int zb5 = 0; zb5 < 5; ++zb5) {
        int z = z0 + 4 * zb5;
        float4 tn[4], pv[4], iv[4];
#pragma unroll
        for (int j = 0; j < 4; ++j) {
            int zl = z + j + 5;
            tn[j] = (zl < NX) ? load_t4(&t[base + zl * N2]) : f4_zero();
            int gi = base + (z + j) * N2;
            pv[j] = *(const float4*)&labels[gi];
            iv[j] = *(const float4*)&inputs[gi];
        }
#pragma unroll
        for (int j = 0; j < 4; ++j) {
            float4 c4 = f4_zero();
#pragma unroll
            for (int d = 0; d < 9; ++d) c4 = f4_axpy(G1[d], win[d], c4);
            float ez = edge_sum(z + j);
            float pc[4] = {pv[j].x, pv[j].y, pv[j].z, pv[j].w};
            float ic[4] = {iv[j].x, iv[j].y, iv[j].z, iv[j].w};
            float cc[4] = {c4.x, c4.y, c4.z, c4.w};
#pragma unroll
            for (int l = 0; l < 4; ++l) {
                float c1 = cx[l] * ez - cc[l];  // conv(1-p) via conv(ones)
                float df0 = ic[l] - m0; df0 *= df0;
                float w0 = __expf(-df0 * df0);
                float df1 = ic[l] - m1; df1 *= df1;
                float w1 = __expf(-df1 * df1);
                n0 += cc[l] * pc[l] * w0;
                d0 += cc[l] * w0;
                n1 += c1 * (1.f - pc[l]) * w1;
                d1 += c1 * w1;
            }
#pragma unroll
            for (int d = 0; d < 8; ++d) win[d] = win[d + 1];
            win[8] = tn[j];
        }
    }
    double vals[4] = {(double)n0, (double)d0, (double)n1, (double)d1};
    block_reduce_to_t0<4>(vals);

    __shared__ int lastFlag;
    if (tid == 0) {
        pZ[blockIdx.x * 4 + 0] = vals[0];
        pZ[blockIdx.x * 4 + 1] = vals[1];
        pZ[blockIdx.x * 4 + 2] = vals[2];
        pZ[blockIdx.x * 4 + 3] = vals[3];
        __threadfence();
        int ticket = atomicAdd(cnt, 1);
        lastFlag = (ticket == NBLK_Z - 1);
    }
    __syncthreads();
    if (lastFlag) {
        __threadfence();
        double a0 = 0, a1 = 0, a2 = 0, a3 = 0;
        for (int i = tid; i < NBLK_Z; i += 256) {
            const double* p = &pZ[4 * i];
            a0 += p[0]; a1 += p[1]; a2 += p[2]; a3 += p[3];
        }
        double v[4] = {a0, a1, a2, a3};
        block_reduce_to_t0<4>(v);
        if (tid == 0) {
            double r0 = fabs(v[0] / (v[1] + 1e-6));
            double r1 = fabs(v[2] / (v[3] + 1e-6));
            out[0] = (float)(2.0 - r0 - r1);
        }
    }
}

extern "C" void kernel_launch(void* const* d_in, const int* in_sizes, int n_in,
                              void* d_out, int out_size, void* d_ws, size_t ws_size,
                              hipStream_t stream) {
    const float* labels = (const float*)d_in[0];
    const float* inputs = (const float*)d_in[1];
    float* out = (float*)d_out;

    // ws layout:
    //   [0)       cnt  : 2 ints (zeroed below)
    //   [256)     pS   : 16000*3 doubles = 384000 B
    //   [384256)  S    : 12 doubles
    //   [384384)  pZ   : 800*4 doubles = 25600 B
    //   [524288)  t    : 160^3 halves = 8,192,000 B
    int*    cnt = (int*)d_ws;
    double* pS  = (double*)((char*)d_ws + 256);
    double* S   = (double*)((char*)d_ws + 384256);
    double* pZ  = (double*)((char*)d_ws + 384384);
    __half* t   = (__half*)((char*)d_ws + 524288);

    hipMemsetAsync(cnt, 0, 8, stream);
    hipLaunchKernelGGL(conv_xy_kernel, dim3(NTILES_XY), dim3(256), 0, stream,
                       labels, inputs, t, pS, S, cnt);
    hipLaunchKernelGGL(conv_z_kernel, dim3(NBLK_Z), dim3(256), 0, stream,
                       t, labels, inputs, S, pZ, out, cnt + 1);
}

// Round 5
// 198.706 us; speedup vs baseline: 4.0045x; 4.0045x over previous
//
#include <hip/hip_runtime.h>
#include <hip/hip_fp16.h>
#include <math.h>

#define NX   160
#define N2   25600        // 160*160
#define N3   4096000      // 160^3
#define NB   4

#define ZPB  4            // z-planes per conv_xy block
#define NBLK_XY 4000      // 5*5 tiles * 40 z-groups * 4 b
#define BLKS_PER_B 1000   // 25 * 40
#define NBLK_Z 800        // 40 x4 * 160 y * 8 zc * 4 b / 256

#define SB_W 36           // 32 cols + 4 pad floats (16B-aligned rows)
#define SB_PLANE (40 * SB_W)

// 1D Gaussian taps exp(-d^2/50), d=-4..4 (NOT normalized, matches reference)
__device__ __constant__ float G1[9] = {
    0.72614903f, 0.83527021f, 0.92311635f, 0.98019867f, 1.0f,
    0.98019867f, 0.92311635f, 0.83527021f, 0.72614903f};

// edge sums: FULL - missing taps at low/high boundary
#define ES_FULL 7.92946852f
__device__ __constant__ float ES_M[4] = {3.46473426f, 2.48453559f, 1.56141924f,
                                         0.72614903f};
__device__ inline float edge_sum(int i) {
    float s = ES_FULL;
    if (i < 4) s -= ES_M[i];
    if (i > NX - 5) s -= ES_M[NX - 1 - i];
    return s;
}

__device__ inline float4 f4_zero() { return make_float4(0.f, 0.f, 0.f, 0.f); }
__device__ inline float4 f4_axpy(float a, float4 b, float4 c) {
    return make_float4(c.x + a * b.x, c.y + a * b.y, c.z + a * b.z, c.w + a * b.w);
}

__device__ inline float4 load_t4(const __half* p) {
    uint2 u = *(const uint2*)p;
    __half2 a = *(const __half2*)&u.x;
    __half2 b = *(const __half2*)&u.y;
    float2 fa = __half22float2(a);
    float2 fb = __half22float2(b);
    return make_float4(fa.x, fa.y, fb.x, fb.y);
}

// block = 256 threads (4 waves). Reduce NV doubles, plain store (NO atomics,
// NO fences — R4 showed per-block __threadfence+ticket costs ~600us).
template <int NV>
__device__ inline void block_reduce_store(double* vals, double* dst) {
    __shared__ double red[4][NV];
    int lane = threadIdx.x & 63;
    int wave = threadIdx.x >> 6;
#pragma unroll
    for (int v = 0; v < NV; ++v) {
        double x = vals[v];
#pragma unroll
        for (int off = 32; off > 0; off >>= 1) x += __shfl_down(x, off, 64);
        if (lane == 0) red[wave][v] = x;
    }
    __syncthreads();
    if (threadIdx.x < NV) {
        int v = threadIdx.x;
        dst[v] = red[0][v] + red[1][v] + red[2][v] + red[3][v];
    }
}

// Separable x+y conv of labels for ZPB z-planes per block.
// x-conv reads labels straight from global (L1 absorbs the 3x float4 overlap),
// y-conv via sB LDS, t stored as fp16. Fused per-batch partial sums -> pS.
__global__ __launch_bounds__(256) void conv_xy_kernel(
    const float* __restrict__ labels, const float* __restrict__ inputs,
    __half* __restrict__ t, double* __restrict__ pS) {
    __shared__ float sB[ZPB * SB_PLANE];

    int bid = blockIdx.x;
    int tileX = bid % 5;
    int tileY = (bid / 5) % 5;
    int zq = (bid / 25) % 40;
    int b = bid / BLKS_PER_B;
    int zbase = zq * ZPB;
    int x0 = tileX * 32, y0 = tileY * 32;
    int tid = threadIdx.x;
    int baseOff = b * N3 + zbase * N2;

    // phase 1: x-conv, ZPB planes x 40 rows x 8 float4 outputs (1280 = 5*256)
    for (int i = tid; i < ZPB * 320; i += 256) {
        int j = i / 320;
        int rem = i - 320 * j;
        int r = rem >> 3, x4 = rem & 7;
        int gy = y0 + r - 4;
        int gxf = x0 + 4 * x4 - 4;   // window start (multiple of 4)
        float w[12];
        if (gy >= 0 && gy < NX) {
            const float* row = &labels[baseOff + j * N2 + gy * NX];
#pragma unroll
            for (int c = 0; c < 3; ++c) {
                int gx = gxf + 4 * c;
                float4 v = (gx >= 0 && gx <= NX - 4) ? *(const float4*)&row[gx]
                                                     : f4_zero();
                w[4 * c] = v.x; w[4 * c + 1] = v.y;
                w[4 * c + 2] = v.z; w[4 * c + 3] = v.w;
            }
        } else {
#pragma unroll
            for (int c = 0; c < 12; ++c) w[c] = 0.f;
        }
        float4 o = f4_zero();
#pragma unroll
        for (int d = 0; d < 9; ++d) {
            float g = G1[d];
            o.x += g * w[d];
            o.y += g * w[d + 1];
            o.z += g * w[d + 2];
            o.w += g * w[d + 3];
        }
        *(float4*)&sB[j * SB_PLANE + r * SB_W + 4 * x4] = o;
    }
    __syncthreads();

    // phase 2: y-conv (ZPB float4 per thread) + fp16 store + fused sums
    int oy = tid >> 3, x4 = tid & 7;
    double sp = 0.0, sip = 0.0, si = 0.0;
#pragma unroll
    for (int j = 0; j < ZPB; ++j) {
        float4 acc = f4_zero();
#pragma unroll
        for (int d = 0; d < 9; ++d) {
            float4 v = *(const float4*)&sB[j * SB_PLANE + (oy + d) * SB_W + 4 * x4];
            acc = f4_axpy(G1[d], v, acc);
        }
        int gi = baseOff + j * N2 + (y0 + oy) * NX + (x0 + 4 * x4);
        __half2 ha = __floats2half2_rn(acc.x, acc.y);
        __half2 hb = __floats2half2_rn(acc.z, acc.w);
        uint2 u;
        u.x = *(unsigned int*)&ha;
        u.y = *(unsigned int*)&hb;
        *(uint2*)&t[gi] = u;   // byte addr 2*gi, gi%4==0 -> 8B aligned

        float4 p = *(const float4*)&labels[gi];
        float4 in = *(const float4*)&inputs[gi];
        sp += (double)(p.x + p.y + p.z + p.w);
        sip += (double)(in.x * p.x + in.y * p.y + in.z * p.z + in.w * p.w);
        si += (double)(in.x + in.y + in.z + in.w);
    }
    double vals[3] = {sp, sip, si};
    block_reduce_store<3>(vals, pS + 3 * bid);
}

// one block per batch: sum 1000 per-block partials -> S[3b+v]
__global__ __launch_bounds__(256) void reduce_S_kernel(
    const double* __restrict__ pS, double* __restrict__ S) {
    int b = blockIdx.x;
    double v0 = 0, v1 = 0, v2 = 0;
    for (int i = threadIdx.x; i < BLKS_PER_B; i += 256) {
        const double* p = pS + 3 * (b * BLKS_PER_B + i);
        v0 += p[0]; v1 += p[1]; v2 += p[2];
    }
    double vals[3] = {v0, v1, v2};
    block_reduce_store<3>(vals, S + 3 * b);
}

// z-conv via register sliding window (float4 = 4 x-cols), t in fp16, batched
// loads (4 z-steps, 12 loads in flight). Per-block partials -> pZ (plain store).
__global__ __launch_bounds__(256) void conv_z_kernel(
    const __half* __restrict__ t, const float* __restrict__ labels,
    const float* __restrict__ inputs, const double* __restrict__ S,
    double* __restrict__ pZ) {
    int tid = threadIdx.x;
    int tidg = blockIdx.x * 256 + tid;  // 0 .. 204799
    int x4 = tidg % 40;           // float4 column; x = 4*x4
    int r = tidg / 40;
    int y = r % NX;
    r /= NX;
    int zc = r % 8;               // z chunk of 20
    int b = r / 8;

    // per-batch means (class 0: p, class 1: 1-p)
    double sp = S[3 * b + 0], sip = S[3 * b + 1], si = S[3 * b + 2];
    const double Nv = (double)N3;
    float m0 = (float)((sip / Nv) / (sp / Nv + 1e-5));
    float m1 = (float)(((si - sip) / Nv) / ((Nv - sp) / Nv + 1e-5));

    int x = x4 * 4;
    float ey = edge_sum(y);
    float cx[4] = {edge_sum(x) * ey, edge_sum(x + 1) * ey,
                   edge_sum(x + 2) * ey, edge_sum(x + 3) * ey};

    int z0 = zc * 20;
    int base = b * N3 + y * NX + x;

    float4 win[9];
#pragma unroll
    for (int d = 0; d < 9; ++d) {
        int z = z0 - 4 + d;
        win[d] = (z >= 0 && z < NX) ? load_t4(&t[base + z * N2]) : f4_zero();
    }

    float n0 = 0.f, d0 = 0.f, n1 = 0.f, d1 = 0.f;
    for (int zb5 = 0; zb5 < 5; ++zb5) {
        int z = z0 + 4 * zb5;
        float4 tn[4], pv[4], iv[4];
#pragma unroll
        for (int j = 0; j < 4; ++j) {
            int zl = z + j + 5;
            tn[j] = (zl < NX) ? load_t4(&t[base + zl * N2]) : f4_zero();
            int gi = base + (z + j) * N2;
            pv[j] = *(const float4*)&labels[gi];
            iv[j] = *(const float4*)&inputs[gi];
        }
#pragma unroll
        for (int j = 0; j < 4; ++j) {
            float4 c4 = f4_zero();
#pragma unroll
            for (int d = 0; d < 9; ++d) c4 = f4_axpy(G1[d], win[d], c4);
            float ez = edge_sum(z + j);
            float pc[4] = {pv[j].x, pv[j].y, pv[j].z, pv[j].w};
            float ic[4] = {iv[j].x, iv[j].y, iv[j].z, iv[j].w};
            float cc[4] = {c4.x, c4.y, c4.z, c4.w};
#pragma unroll
            for (int l = 0; l < 4; ++l) {
                float c1 = cx[l] * ez - cc[l];  // conv(1-p) via conv(ones)
                float df0 = ic[l] - m0; df0 *= df0;
                float w0 = __expf(-df0 * df0);
                float df1 = ic[l] - m1; df1 *= df1;
                float w1 = __expf(-df1 * df1);
                n0 += cc[l] * pc[l] * w0;
                d0 += cc[l] * w0;
                n1 += c1 * (1.f - pc[l]) * w1;
                d1 += c1 * w1;
            }
#pragma unroll
            for (int d = 0; d < 8; ++d) win[d] = win[d + 1];
            win[8] = tn[j];
        }
    }
    double vals[4] = {(double)n0, (double)d0, (double)n1, (double)d1};
    block_reduce_store<4>(vals, pZ + 4 * blockIdx.x);
}

// single block: sum 800 per-block partials, compute final loss
__global__ __launch_bounds__(256) void finalize_kernel(
    const double* __restrict__ pZ, float* __restrict__ out) {
    double a0 = 0, a1 = 0, a2 = 0, a3 = 0;
    for (int i = threadIdx.x; i < NBLK_Z; i += 256) {
        const double* p = &pZ[4 * i];
        a0 += p[0]; a1 += p[1]; a2 += p[2]; a3 += p[3];
    }
    __shared__ double red[4][4];
    int lane = threadIdx.x & 63;
    int wave = threadIdx.x >> 6;
    double vals[4] = {a0, a1, a2, a3};
#pragma unroll
    for (int v = 0; v < 4; ++v) {
        double x = vals[v];
#pragma unroll
        for (int off = 32; off > 0; off >>= 1) x += __shfl_down(x, off, 64);
        if (lane == 0) red[wave][v] = x;
    }
    __syncthreads();
    if (threadIdx.x == 0) {
        double acc[4];
#pragma unroll
        for (int v = 0; v < 4; ++v)
            acc[v] = red[0][v] + red[1][v] + red[2][v] + red[3][v];
        double r0 = fabs(acc[0] / (acc[1] + 1e-6));
        double r1 = fabs(acc[2] / (acc[3] + 1e-6));
        out[0] = (float)(2.0 - r0 - r1);
    }
}

extern "C" void kernel_launch(void* const* d_in, const int* in_sizes, int n_in,
                              void* d_out, int out_size, void* d_ws, size_t ws_size,
                              hipStream_t stream) {
    const float* labels = (const float*)d_in[0];
    const float* inputs = (const float*)d_in[1];
    float* out = (float*)d_out;

    // ws layout:
    //   [0)       pS : 4000*3 doubles = 96000 B
    //   [96000)   S  : 12 doubles
    //   [96128)   pZ : 800*4 doubles = 25600 B
    //   [524288)  t  : 160^3 halves = 8,192,000 B
    double* pS = (double*)d_ws;
    double* S  = (double*)((char*)d_ws + 96000);
    double* pZ = (double*)((char*)d_ws + 96128);
    __half* t  = (__half*)((char*)d_ws + 524288);

    hipLaunchKernelGGL(conv_xy_kernel, dim3(NBLK_XY), dim3(256), 0, stream,
                       labels, inputs, t, pS);
    hipLaunchKernelGGL(reduce_S_kernel, dim3(NB), dim3(256), 0, stream, pS, S);
    hipLaunchKernelGGL(conv_z_kernel, dim3(NBLK_Z), dim3(256), 0, stream,
                       t, labels, inputs, S, pZ);
    hipLaunchKernelGGL(finalize_kernel, dim3(1), dim3(256), 0, stream, pZ, out);
}